// Round 14
// baseline (196.128 us; speedup 1.0000x reference)
//
#include <hip/hip_runtime.h>
#include <math.h>

// Decoder step: B=64, SEQ=1024, EN_H=DE_H=512, ATTN=256, EMBED=256, VOCAB=50000
// d_out layout: [out 64*50000][h1 64*512][h2 64*512][c1 64*512][c2 64*512]

typedef __attribute__((ext_vector_type(8))) short short8;
typedef __attribute__((ext_vector_type(4))) float f32x4;

__device__ __forceinline__ float sigf(float x) { return 1.f / (1.f + expf(-x)); }

__device__ __forceinline__ unsigned short f2bf(float f) {
    unsigned int u = __builtin_bit_cast(unsigned int, f);
    unsigned int r = (u + 0x7fffu + ((u >> 16) & 1u)) >> 16;   // RNE
    return (unsigned short)r;
}

// packed f32 pair -> 2x bf16 in one VALU op (gfx950)
__device__ __forceinline__ unsigned cvt_pk(float lo, float hi) {
    unsigned r;
    asm("v_cvt_pk_bf16_f32 %0, %1, %2" : "=v"(r) : "v"(lo), "v"(hi));
    return r;
}

__device__ __forceinline__ float tanh_fast(float x) {
    float t = __expf(2.f * x);
    return 1.f - 2.f * __builtin_amdgcn_rcpf(1.f + t);
}

// ---------------------------------------------------------------------------
// K1 (fused): blocks 0..63 = prep; blocks 64..95 = convW -> Wt PRE-SWIZZLED
__global__ void k_prep_conv(const int* __restrict__ cur, const float* __restrict__ h0,
                            const float* __restrict__ emb_table, const float* __restrict__ attn_W,
                            float* __restrict__ X1, float* __restrict__ X2, float* __restrict__ X3,
                            float* __restrict__ decW, unsigned short* __restrict__ Wt) {
    int t = threadIdx.x;
    if (blockIdx.x >= 64) {
        __shared__ float tile[64][65];
        int bx = blockIdx.x - 64;
        int kb = (bx & 7) * 64, nb = (bx >> 3) * 64;
        int r0 = t >> 6, c = t & 63;
#pragma unroll
        for (int i = 0; i < 16; ++i) {
            int r = i * 4 + r0;
            tile[r][c] = attn_W[(size_t)(kb + r) * 256 + nb + c];
        }
        __syncthreads();
#pragma unroll
        for (int i = 0; i < 16; ++i) {
            int r = i * 4 + r0;               // n-local
            int n = nb + r;
            int byte = ((n * 128 + ((c >> 3) << 4)) ^ ((r & 7) << 4)) + ((c & 7) << 1);
            *(unsigned short*)((char*)Wt + kb * 512 + byte) = f2bf(tile[c][r]);
        }
        return;
    }
    // ---- prep ----
    __shared__ float dec_s[512];
    int b = blockIdx.x;
    const float* dec = h0 + (size_t)(64 + b) * 512;   // h0[1][b] == h0[-1][b]
    for (int i = t; i < 512; i += 256) {
        float v = dec[i];
        dec_s[i] = v;
        X1[b * 1280 + i] = v;
        X2[b * 1280 + 768 + i] = h0[(size_t)b * 512 + i];
        X3[b * 1024 + 512 + i] = v;
    }
    int row = cur[b];
    float ev = emb_table[(size_t)row * 256 + t];
    X1[b * 1280 + 512 + t] = ev;
    X2[b * 1280 + t] = ev;
    __syncthreads();
    float acc = 0.f;
    for (int k = 0; k < 512; ++k)
        acc += dec_s[k] * attn_W[(size_t)(512 + k) * 256 + t];
    decW[b * 256 + t] = acc;
}

// ---------------------------------------------------------------------------
// K2 (MFMA, software-pipelined, cvt_pk)
__global__ __launch_bounds__(256) void k_scores_mfma(
        const float* __restrict__ enc, const unsigned short* __restrict__ Wt,
        const float* __restrict__ attn_v, const float* __restrict__ decW,
        float* __restrict__ e_out) {
    int s = blockIdx.x, t = threadIdx.x;
    __shared__ __align__(16) unsigned short sA[2][4096];   // 2 x 8 KB
    __shared__ __align__(16) unsigned short sB[16384];     // 32 KB
    const float* arow = enc + (size_t)s * 64 * 512;
    int w = t >> 6, l = t & 63, li = l & 15, lg = l >> 4;
    int sw = (li & 7) << 4;

    int ar0 = t >> 3, akg0 = t & 7;
    int ar1 = (256 + t) >> 3;
    int abyte0 = (ar0 * 128 + akg0 * 16) ^ ((ar0 & 7) << 4);
    int abyte1 = (ar1 * 128 + akg0 * 16) ^ ((ar1 & 7) << 4);
    int bbase = w * 8192 + l * 16;

    f32x4 acc[4][4];
#pragma unroll
    for (int rt = 0; rt < 4; ++rt)
#pragma unroll
        for (int ct = 0; ct < 4; ++ct) acc[rt][ct] = (f32x4){0.f, 0.f, 0.f, 0.f};

    float4 aP[4];
    uint4  bP[8];

#pragma unroll
    for (int i = 0; i < 2; ++i) {
        const float* g = arow + (ar0 + i * 32) * 512 + akg0 * 8;
        aP[2 * i] = *(const float4*)g;
        aP[2 * i + 1] = *(const float4*)(g + 4);
    }
#pragma unroll
    for (int j = 0; j < 8; ++j)
        bP[j] = *(const uint4*)((const char*)Wt + bbase + j * 1024);
    {
        uint4 wv0, wv1;
        wv0.x = cvt_pk(aP[0].x, aP[0].y); wv0.y = cvt_pk(aP[0].z, aP[0].w);
        wv0.z = cvt_pk(aP[1].x, aP[1].y); wv0.w = cvt_pk(aP[1].z, aP[1].w);
        wv1.x = cvt_pk(aP[2].x, aP[2].y); wv1.y = cvt_pk(aP[2].z, aP[2].w);
        wv1.z = cvt_pk(aP[3].x, aP[3].y); wv1.w = cvt_pk(aP[3].z, aP[3].w);
        *(uint4*)((char*)sA[0] + abyte0) = wv0;
        *(uint4*)((char*)sA[0] + abyte1) = wv1;
#pragma unroll
        for (int j = 0; j < 8; ++j)
            *(uint4*)((char*)sB + bbase + j * 1024) = bP[j];
    }
    __syncthreads();

    for (int kk = 0; kk < 8; ++kk) {
        int cur = kk & 1;
        if (kk < 7) {
            int ko = (kk + 1) * 64;
#pragma unroll
            for (int i = 0; i < 2; ++i) {
                const float* g = arow + (ar0 + i * 32) * 512 + ko + akg0 * 8;
                aP[2 * i] = *(const float4*)g;
                aP[2 * i + 1] = *(const float4*)(g + 4);
            }
            const char* src = (const char*)Wt + ((kk + 1) << 15);
#pragma unroll
            for (int j = 0; j < 8; ++j)
                bP[j] = *(const uint4*)(src + bbase + j * 1024);
        }
#pragma unroll
        for (int ks = 0; ks < 2; ++ks) {
            short8 af[4], bf[4];
#pragma unroll
            for (int rt = 0; rt < 4; ++rt) {
                int row = rt * 16 + li;
                af[rt] = *(short8*)((char*)sA[cur] + ((row * 128 + ks * 64 + lg * 16) ^ sw));
            }
#pragma unroll
            for (int ct = 0; ct < 4; ++ct) {
                int n = w * 64 + ct * 16 + li;
                bf[ct] = *(short8*)((char*)sB + ((n * 128 + ks * 64 + lg * 16) ^ sw));
            }
#pragma unroll
            for (int rt = 0; rt < 4; ++rt)
#pragma unroll
                for (int ct = 0; ct < 4; ++ct)
                    acc[rt][ct] = __builtin_amdgcn_mfma_f32_16x16x32_bf16(
                        af[rt], bf[ct], acc[rt][ct], 0, 0, 0);
        }
        if (kk < 7) {
            uint4 wv0, wv1;
            wv0.x = cvt_pk(aP[0].x, aP[0].y); wv0.y = cvt_pk(aP[0].z, aP[0].w);
            wv0.z = cvt_pk(aP[1].x, aP[1].y); wv0.w = cvt_pk(aP[1].z, aP[1].w);
            wv1.x = cvt_pk(aP[2].x, aP[2].y); wv1.y = cvt_pk(aP[2].z, aP[2].w);
            wv1.z = cvt_pk(aP[3].x, aP[3].y); wv1.w = cvt_pk(aP[3].z, aP[3].w);
            *(uint4*)((char*)sA[cur ^ 1] + abyte0) = wv0;
            *(uint4*)((char*)sA[cur ^ 1] + abyte1) = wv1;
#pragma unroll
            for (int j = 0; j < 8; ++j)
                *(uint4*)((char*)sB + bbase + j * 1024) = bP[j];
        }
        __syncthreads();
    }

    float er[4][4];
#pragma unroll
    for (int rt = 0; rt < 4; ++rt)
#pragma unroll
        for (int r = 0; r < 4; ++r) er[rt][r] = 0.f;
#pragma unroll
    for (int ct = 0; ct < 4; ++ct) {
        int a = w * 64 + ct * 16 + li;
        float v = attn_v[a];
#pragma unroll
        for (int rt = 0; rt < 4; ++rt) {
#pragma unroll
            for (int r = 0; r < 4; ++r) {
                int row = rt * 16 + lg * 4 + r;
                float x = acc[rt][ct][r] + decW[row * 256 + a];
                er[rt][r] += tanh_fast(x) * v;
            }
        }
    }
#pragma unroll
    for (int off = 1; off < 16; off <<= 1)
#pragma unroll
        for (int rt = 0; rt < 4; ++rt)
#pragma unroll
            for (int r = 0; r < 4; ++r)
                er[rt][r] += __shfl_xor(er[rt][r], off, 64);
    float* part = (float*)sA[0];
    if (li == 0) {
#pragma unroll
        for (int rt = 0; rt < 4; ++rt)
#pragma unroll
            for (int r = 0; r < 4; ++r)
                part[w * 64 + rt * 16 + lg * 4 + r] = er[rt][r];
    }
    __syncthreads();
    if (t < 64)
        e_out[t * 1024 + s] = part[t] + part[64 + t] + part[128 + t] + part[192 + t];
}

// ---------------------------------------------------------------------------
// K3 (fused softmax + ctx partials) — at HBM ceiling, unchanged
__global__ __launch_bounds__(512) void k_ctx_partial(const float* __restrict__ ebuf,
        const float* __restrict__ mask, const float* __restrict__ enc,
        float* __restrict__ ctxP) {
    int b = blockIdx.x & 63, sc = blockIdx.x >> 6;
    int t = threadIdx.x;
    __shared__ float al[128];
    __shared__ float red[16];
    float v0 = ebuf[b * 1024 + t];
    float v1 = ebuf[b * 1024 + 512 + t];
    v0 = (mask[b * 1024 + t] > 0.f) ? v0 : -1e9f;
    v1 = (mask[b * 1024 + 512 + t] > 0.f) ? v1 : -1e9f;
    float lmax = fmaxf(v0, v1);
#pragma unroll
    for (int off = 32; off > 0; off >>= 1) lmax = fmaxf(lmax, __shfl_xor(lmax, off, 64));
    if ((t & 63) == 0) red[t >> 6] = lmax;
    __syncthreads();
    float m = red[0];
#pragma unroll
    for (int i = 1; i < 8; ++i) m = fmaxf(m, red[i]);
    float lsum = __expf(v0 - m) + __expf(v1 - m);
#pragma unroll
    for (int off = 32; off > 0; off >>= 1) lsum += __shfl_xor(lsum, off, 64);
    if ((t & 63) == 0) red[8 + (t >> 6)] = lsum;
    __syncthreads();
    float tot = red[8];
#pragma unroll
    for (int i = 1; i < 8; ++i) tot += red[8 + i];
    float inv = 1.f / tot;
    if (t < 128) {
        int s = sc * 128 + t;
        float x = ebuf[b * 1024 + s];
        x = (mask[b * 1024 + s] > 0.f) ? x : -1e9f;
        al[t] = __expf(x - m) * inv;
    }
    __syncthreads();
    const float* base = enc + (((size_t)sc * 128 * 64) + b) * 512 + t;
    float a0 = 0.f, a1 = 0.f, a2 = 0.f, a3 = 0.f;
    for (int s = 0; s < 128; s += 4) {
        float x0 = base[(size_t)(s + 0) * 32768];
        float x1 = base[(size_t)(s + 1) * 32768];
        float x2 = base[(size_t)(s + 2) * 32768];
        float x3 = base[(size_t)(s + 3) * 32768];
        a0 += al[s] * x0; a1 += al[s + 1] * x1; a2 += al[s + 2] * x2; a3 += al[s + 3] * x3;
    }
    ctxP[((size_t)sc * 64 + b) * 512 + t] = a0 + a1 + a2 + a3;
}

// ---------------------------------------------------------------------------
// K4: context-gate GEMM (PROVEN, ksplit 4) -> P (4x64x512)
__global__ __launch_bounds__(1024) void k_gemm_cg(const float* __restrict__ X,
        const float* __restrict__ ctxP, const float* __restrict__ Wkn,
        float* __restrict__ P) {
    int n0 = blockIdx.x * 64, sp = blockIdx.y;
    int t = threadIdx.x, tc = t & 63, tr = t >> 6;
    __shared__ __align__(16) float As[64 * 68];
    __shared__ __align__(16) float Wc[64 * 68];
    float acc[4] = {0.f, 0.f, 0.f, 0.f};
    for (int c = 0; c < 5; ++c) {
        int k0 = sp * 320 + c * 64;
        __syncthreads();
#pragma unroll
        for (int i = 0; i < 4; ++i) {
            int idx = i * 1024 + t; int row = idx >> 6; int k = idx & 63;
            int gk = k0 + k;
            float v;
            if (gk < 768) {
                v = X[row * 1280 + gk];
            } else {
                int h = gk - 768;
                v = 0.f;
#pragma unroll
                for (int sc = 0; sc < 8; ++sc)
                    v += ctxP[((size_t)sc * 64 + row) * 512 + h];
            }
            As[k * 68 + row] = v;
        }
#pragma unroll
        for (int i = 0; i < 4; ++i) {
            int idx = i * 1024 + t; int k = idx >> 6; int cc = idx & 63;
            Wc[k * 68 + cc] = Wkn[(size_t)(k0 + k) * 512 + n0 + cc];
        }
        __syncthreads();
#pragma unroll 8
        for (int k = 0; k < 64; ++k) {
            float4 a = *(const float4*)&As[k * 68 + 4 * tr];
            float wv = Wc[k * 68 + tc];
            acc[0] += a.x * wv; acc[1] += a.y * wv; acc[2] += a.z * wv; acc[3] += a.w * wv;
        }
    }
    float* Pp = P + (size_t)sp * 32768;
#pragma unroll
    for (int j = 0; j < 4; ++j) Pp[(4 * tr + j) * 512 + n0 + tc] = acc[j];
}

// ---------------------------------------------------------------------------
// K5: cg finalize (PROVEN) -> X2 gate slab
__global__ void k_cg_fin(const float* __restrict__ P, const float* __restrict__ cg_b,
                         const float* __restrict__ ctxP, float* __restrict__ X2) {
    int idx = blockIdx.x * 256 + threadIdx.x;          // 32768
    int b = idx >> 9, h = idx & 511;
    float g = cg_b[h];
#pragma unroll
    for (int sp = 0; sp < 4; ++sp) g += P[sp * 32768 + idx];
    float ctx = 0.f;
#pragma unroll
    for (int sc = 0; sc < 8; ++sc) ctx += ctxP[((size_t)sc * 64 + b) * 512 + h];
    X2[b * 1280 + 256 + h] = sigf(g) * ctx;
}

// ---------------------------------------------------------------------------
// K6: LSTM GEMM (PROVEN), grid (32,4), ksplit 4
__global__ __launch_bounds__(1024) void k_gemm_lstm(const float* __restrict__ X, int ldx,
        const float* __restrict__ W1, int K1, const float* __restrict__ W2, int K2,
        int kchunks, float* __restrict__ P) {
    int n0 = blockIdx.x * 64, sp = blockIdx.y;
    int t = threadIdx.x, tc = t & 63, tr = t >> 6;
    __shared__ __align__(16) float As[64 * 68];
    __shared__ __align__(16) float Wc[64 * 68];
    float acc[4] = {0.f, 0.f, 0.f, 0.f};
    for (int c = 0; c < kchunks; ++c) {
        int k0 = (sp * kchunks + c) * 64;
        __syncthreads();
#pragma unroll
        for (int i = 0; i < 4; ++i) {
            int idx = i * 1024 + t; int row = idx >> 6; int k = idx & 63;
            As[k * 68 + row] = X[row * ldx + k0 + k];
        }
#pragma unroll
        for (int i = 0; i < 4; ++i) {
            int idx = i * 1024 + t; int cc = idx >> 6; int k = idx & 63;
            int gk = k0 + k; int j = n0 + cc;
            float wv = (gk < K1) ? W1[(size_t)j * K1 + gk] : W2[(size_t)j * K2 + gk - K1];
            Wc[k * 68 + cc] = wv;
        }
        __syncthreads();
#pragma unroll 8
        for (int k = 0; k < 64; ++k) {
            float4 a = *(const float4*)&As[k * 68 + 4 * tr];
            float wv = Wc[k * 68 + tc];
            acc[0] += a.x * wv; acc[1] += a.y * wv; acc[2] += a.z * wv; acc[3] += a.w * wv;
        }
    }
    float* Pp = P + (size_t)sp * 64 * 2048;
#pragma unroll
    for (int j = 0; j < 4; ++j) Pp[(4 * tr + j) * 2048 + n0 + tc] = acc[j];
}

// ---------------------------------------------------------------------------
// K7: LSTM finalize (PROVEN, 4 partials)
__global__ void k_lstm_fin(const float* __restrict__ P, const float* __restrict__ bih,
                           const float* __restrict__ bhh, const float* __restrict__ c0,
                           int layer, float* __restrict__ oh, float* __restrict__ oc,
                           float* __restrict__ X3out) {
    int idx = blockIdx.x * 256 + threadIdx.x;
    int b = idx >> 9, h = idx & 511;
    float gi = bih[h] + bhh[h];
    float gf = bih[512 + h] + bhh[512 + h];
    float gg = bih[1024 + h] + bhh[1024 + h];
    float go = bih[1536 + h] + bhh[1536 + h];
#pragma unroll
    for (int sp = 0; sp < 4; ++sp) {
        const float* Pp = P + sp * 131072 + b * 2048;
        gi += Pp[h]; gf += Pp[512 + h]; gg += Pp[1024 + h]; go += Pp[1536 + h];
    }
    float cp = c0[layer * 32768 + b * 512 + h];
    float cn = sigf(gf) * cp + sigf(gi) * tanhf(gg);
    float hn = sigf(go) * tanhf(cn);
    oh[b * 512 + h] = hn;
    oc[b * 512 + h] = cn;
    if (X3out) X3out[b * 1024 + h] = hn;
}

// ---------------------------------------------------------------------------
// K8 (MFMA, phase-staged): out = h2 @ out_W + out_b. Tile 64x64xK512,
// grid 782. A staged ONCE per 256-K phase (sA 64x256 bf16 = 32 KB, swizzled);
// per-phase compute is 8 unrolled sub-chunks of {B-loads -> cvt -> MFMA} with
// NO barriers between, so out_W loads stay in flight (fixes the 16-barrier
// vmcnt(0)-drain structure that left outproj at 47-70us vs ~17us floor).
__global__ __launch_bounds__(256) void k_outproj_mfma(
        const float* __restrict__ h2, const float* __restrict__ out_W,
        const float* __restrict__ out_b, float* __restrict__ out) {
    int t = threadIdx.x;
    int n0 = blockIdx.x * 64;
    int w = t >> 6, l = t & 63, li = l & 15, lg = l >> 4;
    int sw = (li & 7) << 4;
    __shared__ __align__(16) unsigned short sA[16384];  // 64 rows x 256 k bf16

    f32x4 acc[4];
#pragma unroll
    for (int rt = 0; rt < 4; ++rt) acc[rt] = (f32x4){0.f, 0.f, 0.f, 0.f};
    int col = n0 + w * 16 + li;
    int colc = (col < 50000) ? col : 49999;

    for (int ph = 0; ph < 2; ++ph) {
        __syncthreads();
        // stage A: 64 rows x 256 k (f32 -> bf16, swizzled), once per phase
#pragma unroll
        for (int i = 0; i < 8; ++i) {
            int idx = i * 256 + t;              // 0..2047
            int row = idx >> 5, kg = idx & 31;
            const float* g = h2 + row * 512 + ph * 256 + kg * 8;
            float4 p0 = *(const float4*)g;
            float4 p1 = *(const float4*)(g + 4);
            uint4 wv;
            wv.x = cvt_pk(p0.x, p0.y); wv.y = cvt_pk(p0.z, p0.w);
            wv.z = cvt_pk(p1.x, p1.y); wv.w = cvt_pk(p1.z, p1.w);
            int byte = (row * 512 + kg * 16) ^ ((row & 7) << 4);
            *(uint4*)((char*)sA + byte) = wv;
        }
        __syncthreads();
        // barrier-free streaming compute over this phase's 256 k
#pragma unroll
        for (int cc = 0; cc < 4; ++cc) {
#pragma unroll
            for (int ks = 0; ks < 2; ++ks) {
                int kk = ph * 256 + cc * 64 + ks * 32;
                const float* wp = out_W + (size_t)(kk + lg * 8) * 50000 + colc;
                uint4 qv;
                float v0 = wp[0],          v1 = wp[50000];
                float v2 = wp[2 * 50000],  v3 = wp[3 * 50000];
                float v4 = wp[4 * 50000],  v5 = wp[5 * 50000];
                float v6 = wp[6 * 50000],  v7 = wp[7 * 50000];
                qv.x = cvt_pk(v0, v1); qv.y = cvt_pk(v2, v3);
                qv.z = cvt_pk(v4, v5); qv.w = cvt_pk(v6, v7);
                short8 bf = *(short8*)&qv;
                short8 af[4];
#pragma unroll
                for (int rt = 0; rt < 4; ++rt) {
                    int row = rt * 16 + li;
                    af[rt] = *(short8*)((char*)sA +
                        ((row * 512 + cc * 128 + ks * 64 + lg * 16) ^ sw));
                }
#pragma unroll
                for (int rt = 0; rt < 4; ++rt)
                    acc[rt] = __builtin_amdgcn_mfma_f32_16x16x32_bf16(
                        af[rt], bf, acc[rt], 0, 0, 0);
            }
        }
    }
    if (col < 50000) {
        float bias = out_b[col];
#pragma unroll
        for (int rt = 0; rt < 4; ++rt)
#pragma unroll
            for (int r = 0; r < 4; ++r) {
                int row = rt * 16 + lg * 4 + r;
                out[(size_t)row * 50000 + col] = acc[rt][r] + bias;
            }
    }
}

// ---------------------------------------------------------------------------
extern "C" void kernel_launch(void* const* d_in, const int* in_sizes, int n_in,
                              void* d_out, int out_size, void* d_ws, size_t ws_size,
                              hipStream_t stream) {
    const int*   cur       = (const int*)d_in[0];
    const float* h0        = (const float*)d_in[1];
    const float* c0        = (const float*)d_in[2];
    const float* enc       = (const float*)d_in[3];
    const float* mask      = (const float*)d_in[4];
    const float* emb_table = (const float*)d_in[5];
    const float* attn_W    = (const float*)d_in[6];
    const float* attn_v    = (const float*)d_in[7];
    const float* cg_W      = (const float*)d_in[8];
    const float* cg_b      = (const float*)d_in[9];
    const float* Wih0      = (const float*)d_in[10];
    const float* Whh0      = (const float*)d_in[11];
    const float* bih0      = (const float*)d_in[12];
    const float* bhh0      = (const float*)d_in[13];
    const float* Wih1      = (const float*)d_in[14];
    const float* Whh1      = (const float*)d_in[15];
    const float* bih1      = (const float*)d_in[16];
    const float* bhh1      = (const float*)d_in[17];
    const float* out_W     = (const float*)d_in[18];
    const float* out_b     = (const float*)d_in[19];
    float* out = (float*)d_out;

    // ws layout (floats) — high-water 1,097,728 floats = 4.39 MB:
    float* w    = (float*)d_ws;
    float* X1   = w;                  // 81920   (dec|emb|-)
    float* X2   = X1 + 81920;         // 81920   (emb | gate | h0[0])
    float* X3   = X2 + 81920;         // 65536   (h1-slot | h0[1])
    float* decW = X3 + 65536;         // 16384
    float* eb   = decW + 16384;       // 65536   raw scores [b][s]
    float* P    = eb + 65536;         // 524288  partials (4x131072); Wt overlays
    float* ctxP = P + 524288;         // 262144  ctx partials
    unsigned short* Wt = (unsigned short*)P;   // bf16 256KB, consumed before P written

    float* outH = out + 3200000;      // h1 then h2
    float* outC = out + 3265536;      // c1 then c2

    hipLaunchKernelGGL(k_prep_conv, dim3(96), dim3(256), 0, stream,
                       cur, h0, emb_table, attn_W, X1, X2, X3, decW, Wt);
    hipLaunchKernelGGL(k_scores_mfma, dim3(1024), dim3(256), 0, stream,
                       enc, Wt, attn_v, decW, eb);
    hipLaunchKernelGGL(k_ctx_partial, dim3(512), dim3(512), 0, stream,
                       eb, mask, enc, ctxP);
    hipLaunchKernelGGL(k_gemm_cg, dim3(8, 4), dim3(1024), 0, stream,
                       X1, ctxP, cg_W, P);
    hipLaunchKernelGGL(k_cg_fin, dim3(128), dim3(256), 0, stream, P, cg_b, ctxP, X2);
    hipLaunchKernelGGL(k_gemm_lstm, dim3(32, 4), dim3(1024), 0, stream,
                       X2, 1280, Wih0, 768, Whh0, 512, 5, P);
    hipLaunchKernelGGL(k_lstm_fin, dim3(128), dim3(256), 0, stream,
                       P, bih0, bhh0, c0, 0, outH, outC, X3);
    hipLaunchKernelGGL(k_gemm_lstm, dim3(32, 4), dim3(1024), 0, stream,
                       X3, 1024, Wih1, 512, Whh1, 512, 4, P);
    hipLaunchKernelGGL(k_lstm_fin, dim3(128), dim3(256), 0, stream,
                       P, bih1, bhh1, c0, 1, outH + 32768, outC + 32768, (float*)nullptr);
    hipLaunchKernelGGL(k_outproj_mfma, dim3(782), dim3(256), 0, stream,
                       outH + 32768, out_W, out_b, out);
}

// Round 15
// 176.935 us; speedup vs baseline: 1.1085x; 1.1085x over previous
//
#include <hip/hip_runtime.h>
#include <math.h>

// Decoder step: B=64, SEQ=1024, EN_H=DE_H=512, ATTN=256, EMBED=256, VOCAB=50000
// d_out layout: [out 64*50000][h1 64*512][h2 64*512][c1 64*512][c2 64*512]

typedef __attribute__((ext_vector_type(8))) short short8;
typedef __attribute__((ext_vector_type(4))) float f32x4;

__device__ __forceinline__ float sigf(float x) { return 1.f / (1.f + expf(-x)); }

__device__ __forceinline__ unsigned short f2bf(float f) {
    unsigned int u = __builtin_bit_cast(unsigned int, f);
    unsigned int r = (u + 0x7fffu + ((u >> 16) & 1u)) >> 16;   // RNE
    return (unsigned short)r;
}

// packed f32 pair -> 2x bf16 in one VALU op (gfx950)
__device__ __forceinline__ unsigned cvt_pk(float lo, float hi) {
    unsigned r;
    asm("v_cvt_pk_bf16_f32 %0, %1, %2" : "=v"(r) : "v"(lo), "v"(hi));
    return r;
}

__device__ __forceinline__ float tanh_fast(float x) {
    float t = __expf(2.f * x);
    return 1.f - 2.f * __builtin_amdgcn_rcpf(1.f + t);
}

// ---------------------------------------------------------------------------
// K1 (fused): blocks 0..63 = prep; blocks 64..95 = convW -> Wt PRE-SWIZZLED
__global__ void k_prep_conv(const int* __restrict__ cur, const float* __restrict__ h0,
                            const float* __restrict__ emb_table, const float* __restrict__ attn_W,
                            float* __restrict__ X1, float* __restrict__ X2, float* __restrict__ X3,
                            float* __restrict__ decW, unsigned short* __restrict__ Wt) {
    int t = threadIdx.x;
    if (blockIdx.x >= 64) {
        __shared__ float tile[64][65];
        int bx = blockIdx.x - 64;
        int kb = (bx & 7) * 64, nb = (bx >> 3) * 64;
        int r0 = t >> 6, c = t & 63;
#pragma unroll
        for (int i = 0; i < 16; ++i) {
            int r = i * 4 + r0;
            tile[r][c] = attn_W[(size_t)(kb + r) * 256 + nb + c];
        }
        __syncthreads();
#pragma unroll
        for (int i = 0; i < 16; ++i) {
            int r = i * 4 + r0;               // n-local
            int n = nb + r;
            int byte = ((n * 128 + ((c >> 3) << 4)) ^ ((r & 7) << 4)) + ((c & 7) << 1);
            *(unsigned short*)((char*)Wt + kb * 512 + byte) = f2bf(tile[c][r]);
        }
        return;
    }
    // ---- prep ----
    __shared__ float dec_s[512];
    int b = blockIdx.x;
    const float* dec = h0 + (size_t)(64 + b) * 512;   // h0[1][b] == h0[-1][b]
    for (int i = t; i < 512; i += 256) {
        float v = dec[i];
        dec_s[i] = v;
        X1[b * 1280 + i] = v;
        X2[b * 1280 + 768 + i] = h0[(size_t)b * 512 + i];
        X3[b * 1024 + 512 + i] = v;
    }
    int row = cur[b];
    float ev = emb_table[(size_t)row * 256 + t];
    X1[b * 1280 + 512 + t] = ev;
    X2[b * 1280 + t] = ev;
    __syncthreads();
    float acc = 0.f;
    for (int k = 0; k < 512; ++k)
        acc += dec_s[k] * attn_W[(size_t)(512 + k) * 256 + t];
    decW[b * 256 + t] = acc;
}

// ---------------------------------------------------------------------------
// K2 (MFMA, software-pipelined, cvt_pk)
__global__ __launch_bounds__(256) void k_scores_mfma(
        const float* __restrict__ enc, const unsigned short* __restrict__ Wt,
        const float* __restrict__ attn_v, const float* __restrict__ decW,
        float* __restrict__ e_out) {
    int s = blockIdx.x, t = threadIdx.x;
    __shared__ __align__(16) unsigned short sA[2][4096];   // 2 x 8 KB
    __shared__ __align__(16) unsigned short sB[16384];     // 32 KB
    const float* arow = enc + (size_t)s * 64 * 512;
    int w = t >> 6, l = t & 63, li = l & 15, lg = l >> 4;
    int sw = (li & 7) << 4;

    int ar0 = t >> 3, akg0 = t & 7;
    int ar1 = (256 + t) >> 3;
    int abyte0 = (ar0 * 128 + akg0 * 16) ^ ((ar0 & 7) << 4);
    int abyte1 = (ar1 * 128 + akg0 * 16) ^ ((ar1 & 7) << 4);
    int bbase = w * 8192 + l * 16;

    f32x4 acc[4][4];
#pragma unroll
    for (int rt = 0; rt < 4; ++rt)
#pragma unroll
        for (int ct = 0; ct < 4; ++ct) acc[rt][ct] = (f32x4){0.f, 0.f, 0.f, 0.f};

    float4 aP[4];
    uint4  bP[8];

#pragma unroll
    for (int i = 0; i < 2; ++i) {
        const float* g = arow + (ar0 + i * 32) * 512 + akg0 * 8;
        aP[2 * i] = *(const float4*)g;
        aP[2 * i + 1] = *(const float4*)(g + 4);
    }
#pragma unroll
    for (int j = 0; j < 8; ++j)
        bP[j] = *(const uint4*)((const char*)Wt + bbase + j * 1024);
    {
        uint4 wv0, wv1;
        wv0.x = cvt_pk(aP[0].x, aP[0].y); wv0.y = cvt_pk(aP[0].z, aP[0].w);
        wv0.z = cvt_pk(aP[1].x, aP[1].y); wv0.w = cvt_pk(aP[1].z, aP[1].w);
        wv1.x = cvt_pk(aP[2].x, aP[2].y); wv1.y = cvt_pk(aP[2].z, aP[2].w);
        wv1.z = cvt_pk(aP[3].x, aP[3].y); wv1.w = cvt_pk(aP[3].z, aP[3].w);
        *(uint4*)((char*)sA[0] + abyte0) = wv0;
        *(uint4*)((char*)sA[0] + abyte1) = wv1;
#pragma unroll
        for (int j = 0; j < 8; ++j)
            *(uint4*)((char*)sB + bbase + j * 1024) = bP[j];
    }
    __syncthreads();

    for (int kk = 0; kk < 8; ++kk) {
        int cur = kk & 1;
        if (kk < 7) {
            int ko = (kk + 1) * 64;
#pragma unroll
            for (int i = 0; i < 2; ++i) {
                const float* g = arow + (ar0 + i * 32) * 512 + ko + akg0 * 8;
                aP[2 * i] = *(const float4*)g;
                aP[2 * i + 1] = *(const float4*)(g + 4);
            }
            const char* src = (const char*)Wt + ((kk + 1) << 15);
#pragma unroll
            for (int j = 0; j < 8; ++j)
                bP[j] = *(const uint4*)(src + bbase + j * 1024);
        }
#pragma unroll
        for (int ks = 0; ks < 2; ++ks) {
            short8 af[4], bf[4];
#pragma unroll
            for (int rt = 0; rt < 4; ++rt) {
                int row = rt * 16 + li;
                af[rt] = *(short8*)((char*)sA[cur] + ((row * 128 + ks * 64 + lg * 16) ^ sw));
            }
#pragma unroll
            for (int ct = 0; ct < 4; ++ct) {
                int n = w * 64 + ct * 16 + li;
                bf[ct] = *(short8*)((char*)sB + ((n * 128 + ks * 64 + lg * 16) ^ sw));
            }
#pragma unroll
            for (int rt = 0; rt < 4; ++rt)
#pragma unroll
                for (int ct = 0; ct < 4; ++ct)
                    acc[rt][ct] = __builtin_amdgcn_mfma_f32_16x16x32_bf16(
                        af[rt], bf[ct], acc[rt][ct], 0, 0, 0);
        }
        if (kk < 7) {
            uint4 wv0, wv1;
            wv0.x = cvt_pk(aP[0].x, aP[0].y); wv0.y = cvt_pk(aP[0].z, aP[0].w);
            wv0.z = cvt_pk(aP[1].x, aP[1].y); wv0.w = cvt_pk(aP[1].z, aP[1].w);
            wv1.x = cvt_pk(aP[2].x, aP[2].y); wv1.y = cvt_pk(aP[2].z, aP[2].w);
            wv1.z = cvt_pk(aP[3].x, aP[3].y); wv1.w = cvt_pk(aP[3].z, aP[3].w);
            *(uint4*)((char*)sA[cur ^ 1] + abyte0) = wv0;
            *(uint4*)((char*)sA[cur ^ 1] + abyte1) = wv1;
#pragma unroll
            for (int j = 0; j < 8; ++j)
                *(uint4*)((char*)sB + bbase + j * 1024) = bP[j];
        }
        __syncthreads();
    }

    float er[4][4];
#pragma unroll
    for (int rt = 0; rt < 4; ++rt)
#pragma unroll
        for (int r = 0; r < 4; ++r) er[rt][r] = 0.f;
#pragma unroll
    for (int ct = 0; ct < 4; ++ct) {
        int a = w * 64 + ct * 16 + li;
        float v = attn_v[a];
#pragma unroll
        for (int rt = 0; rt < 4; ++rt) {
#pragma unroll
            for (int r = 0; r < 4; ++r) {
                int row = rt * 16 + lg * 4 + r;
                float x = acc[rt][ct][r] + decW[row * 256 + a];
                er[rt][r] += tanh_fast(x) * v;
            }
        }
    }
#pragma unroll
    for (int off = 1; off < 16; off <<= 1)
#pragma unroll
        for (int rt = 0; rt < 4; ++rt)
#pragma unroll
            for (int r = 0; r < 4; ++r)
                er[rt][r] += __shfl_xor(er[rt][r], off, 64);
    float* part = (float*)sA[0];
    if (li == 0) {
#pragma unroll
        for (int rt = 0; rt < 4; ++rt)
#pragma unroll
            for (int r = 0; r < 4; ++r)
                part[w * 64 + rt * 16 + lg * 4 + r] = er[rt][r];
    }
    __syncthreads();
    if (t < 64)
        e_out[t * 1024 + s] = part[t] + part[64 + t] + part[128 + t] + part[192 + t];
}

// ---------------------------------------------------------------------------
// K3 (fused softmax + ctx partials) — at HBM ceiling, unchanged
__global__ __launch_bounds__(512) void k_ctx_partial(const float* __restrict__ ebuf,
        const float* __restrict__ mask, const float* __restrict__ enc,
        float* __restrict__ ctxP) {
    int b = blockIdx.x & 63, sc = blockIdx.x >> 6;
    int t = threadIdx.x;
    __shared__ float al[128];
    __shared__ float red[16];
    float v0 = ebuf[b * 1024 + t];
    float v1 = ebuf[b * 1024 + 512 + t];
    v0 = (mask[b * 1024 + t] > 0.f) ? v0 : -1e9f;
    v1 = (mask[b * 1024 + 512 + t] > 0.f) ? v1 : -1e9f;
    float lmax = fmaxf(v0, v1);
#pragma unroll
    for (int off = 32; off > 0; off >>= 1) lmax = fmaxf(lmax, __shfl_xor(lmax, off, 64));
    if ((t & 63) == 0) red[t >> 6] = lmax;
    __syncthreads();
    float m = red[0];
#pragma unroll
    for (int i = 1; i < 8; ++i) m = fmaxf(m, red[i]);
    float lsum = __expf(v0 - m) + __expf(v1 - m);
#pragma unroll
    for (int off = 32; off > 0; off >>= 1) lsum += __shfl_xor(lsum, off, 64);
    if ((t & 63) == 0) red[8 + (t >> 6)] = lsum;
    __syncthreads();
    float tot = red[8];
#pragma unroll
    for (int i = 1; i < 8; ++i) tot += red[8 + i];
    float inv = 1.f / tot;
    if (t < 128) {
        int s = sc * 128 + t;
        float x = ebuf[b * 1024 + s];
        x = (mask[b * 1024 + s] > 0.f) ? x : -1e9f;
        al[t] = __expf(x - m) * inv;
    }
    __syncthreads();
    const float* base = enc + (((size_t)sc * 128 * 64) + b) * 512 + t;
    float a0 = 0.f, a1 = 0.f, a2 = 0.f, a3 = 0.f;
    for (int s = 0; s < 128; s += 4) {
        float x0 = base[(size_t)(s + 0) * 32768];
        float x1 = base[(size_t)(s + 1) * 32768];
        float x2 = base[(size_t)(s + 2) * 32768];
        float x3 = base[(size_t)(s + 3) * 32768];
        a0 += al[s] * x0; a1 += al[s + 1] * x1; a2 += al[s + 2] * x2; a3 += al[s + 3] * x3;
    }
    ctxP[((size_t)sc * 64 + b) * 512 + t] = a0 + a1 + a2 + a3;
}

// ---------------------------------------------------------------------------
// K4: context-gate GEMM (PROVEN, ksplit 4) -> P (4x64x512)
__global__ __launch_bounds__(1024) void k_gemm_cg(const float* __restrict__ X,
        const float* __restrict__ ctxP, const float* __restrict__ Wkn,
        float* __restrict__ P) {
    int n0 = blockIdx.x * 64, sp = blockIdx.y;
    int t = threadIdx.x, tc = t & 63, tr = t >> 6;
    __shared__ __align__(16) float As[64 * 68];
    __shared__ __align__(16) float Wc[64 * 68];
    float acc[4] = {0.f, 0.f, 0.f, 0.f};
    for (int c = 0; c < 5; ++c) {
        int k0 = sp * 320 + c * 64;
        __syncthreads();
#pragma unroll
        for (int i = 0; i < 4; ++i) {
            int idx = i * 1024 + t; int row = idx >> 6; int k = idx & 63;
            int gk = k0 + k;
            float v;
            if (gk < 768) {
                v = X[row * 1280 + gk];
            } else {
                int h = gk - 768;
                v = 0.f;
#pragma unroll
                for (int sc = 0; sc < 8; ++sc)
                    v += ctxP[((size_t)sc * 64 + row) * 512 + h];
            }
            As[k * 68 + row] = v;
        }
#pragma unroll
        for (int i = 0; i < 4; ++i) {
            int idx = i * 1024 + t; int k = idx >> 6; int cc = idx & 63;
            Wc[k * 68 + cc] = Wkn[(size_t)(k0 + k) * 512 + n0 + cc];
        }
        __syncthreads();
#pragma unroll 8
        for (int k = 0; k < 64; ++k) {
            float4 a = *(const float4*)&As[k * 68 + 4 * tr];
            float wv = Wc[k * 68 + tc];
            acc[0] += a.x * wv; acc[1] += a.y * wv; acc[2] += a.z * wv; acc[3] += a.w * wv;
        }
    }
    float* Pp = P + (size_t)sp * 32768;
#pragma unroll
    for (int j = 0; j < 4; ++j) Pp[(4 * tr + j) * 512 + n0 + tc] = acc[j];
}

// ---------------------------------------------------------------------------
// K5: cg finalize (PROVEN) -> X2 gate slab
__global__ void k_cg_fin(const float* __restrict__ P, const float* __restrict__ cg_b,
                         const float* __restrict__ ctxP, float* __restrict__ X2) {
    int idx = blockIdx.x * 256 + threadIdx.x;          // 32768
    int b = idx >> 9, h = idx & 511;
    float g = cg_b[h];
#pragma unroll
    for (int sp = 0; sp < 4; ++sp) g += P[sp * 32768 + idx];
    float ctx = 0.f;
#pragma unroll
    for (int sc = 0; sc < 8; ++sc) ctx += ctxP[((size_t)sc * 64 + b) * 512 + h];
    X2[b * 1280 + 256 + h] = sigf(g) * ctx;
}

// ---------------------------------------------------------------------------
// K6: LSTM GEMM (PROVEN), grid (32,4), ksplit 4
__global__ __launch_bounds__(1024) void k_gemm_lstm(const float* __restrict__ X, int ldx,
        const float* __restrict__ W1, int K1, const float* __restrict__ W2, int K2,
        int kchunks, float* __restrict__ P) {
    int n0 = blockIdx.x * 64, sp = blockIdx.y;
    int t = threadIdx.x, tc = t & 63, tr = t >> 6;
    __shared__ __align__(16) float As[64 * 68];
    __shared__ __align__(16) float Wc[64 * 68];
    float acc[4] = {0.f, 0.f, 0.f, 0.f};
    for (int c = 0; c < kchunks; ++c) {
        int k0 = (sp * kchunks + c) * 64;
        __syncthreads();
#pragma unroll
        for (int i = 0; i < 4; ++i) {
            int idx = i * 1024 + t; int row = idx >> 6; int k = idx & 63;
            As[k * 68 + row] = X[row * ldx + k0 + k];
        }
#pragma unroll
        for (int i = 0; i < 4; ++i) {
            int idx = i * 1024 + t; int cc = idx >> 6; int k = idx & 63;
            int gk = k0 + k; int j = n0 + cc;
            float wv = (gk < K1) ? W1[(size_t)j * K1 + gk] : W2[(size_t)j * K2 + gk - K1];
            Wc[k * 68 + cc] = wv;
        }
        __syncthreads();
#pragma unroll 8
        for (int k = 0; k < 64; ++k) {
            float4 a = *(const float4*)&As[k * 68 + 4 * tr];
            float wv = Wc[k * 68 + tc];
            acc[0] += a.x * wv; acc[1] += a.y * wv; acc[2] += a.z * wv; acc[3] += a.w * wv;
        }
    }
    float* Pp = P + (size_t)sp * 64 * 2048;
#pragma unroll
    for (int j = 0; j < 4; ++j) Pp[(4 * tr + j) * 2048 + n0 + tc] = acc[j];
}

// ---------------------------------------------------------------------------
// K7: LSTM finalize (PROVEN, 4 partials)
__global__ void k_lstm_fin(const float* __restrict__ P, const float* __restrict__ bih,
                           const float* __restrict__ bhh, const float* __restrict__ c0,
                           int layer, float* __restrict__ oh, float* __restrict__ oc,
                           float* __restrict__ X3out) {
    int idx = blockIdx.x * 256 + threadIdx.x;
    int b = idx >> 9, h = idx & 511;
    float gi = bih[h] + bhh[h];
    float gf = bih[512 + h] + bhh[512 + h];
    float gg = bih[1024 + h] + bhh[1024 + h];
    float go = bih[1536 + h] + bhh[1536 + h];
#pragma unroll
    for (int sp = 0; sp < 4; ++sp) {
        const float* Pp = P + sp * 131072 + b * 2048;
        gi += Pp[h]; gf += Pp[512 + h]; gg += Pp[1024 + h]; go += Pp[1536 + h];
    }
    float cp = c0[layer * 32768 + b * 512 + h];
    float cn = sigf(gf) * cp + sigf(gi) * tanhf(gg);
    float hn = sigf(go) * tanhf(cn);
    oh[b * 512 + h] = hn;
    oc[b * 512 + h] = cn;
    if (X3out) X3out[b * 1024 + h] = hn;
}

// ---------------------------------------------------------------------------
// K8 (MFMA, 8-wave in-block K-split): out = h2 @ out_W + out_b.
// N=64/block, grid 782. Waves 0-3: cols (w&3)*16, k [0,256); waves 4-7: same
// cols, k [256,512). 24 waves/CU (2x R13's TLP) to hide out_W load latency.
// Final cross-half reduce via 16KB LDS (b128 pattern, conflict-free).
__global__ __launch_bounds__(512) void k_outproj_mfma(
        const float* __restrict__ h2, const float* __restrict__ out_W,
        const float* __restrict__ out_b, float* __restrict__ out) {
    int t = threadIdx.x;
    int n0 = blockIdx.x * 64;
    int w = t >> 6, l = t & 63, li = l & 15, lg = l >> 4;
    int sw = (li & 7) << 4;
    int wc = w & 3, kh = w >> 2;                      // col-group, k-half
    __shared__ __align__(16) unsigned short sA[2][4096];  // [half][64 rows x 64 k]

    f32x4 acc[4];
#pragma unroll
    for (int rt = 0; rt < 4; ++rt) acc[rt] = (f32x4){0.f, 0.f, 0.f, 0.f};
    int col = n0 + wc * 16 + li;
    int colc = (col < 50000) ? col : 49999;

    int srow = t >> 3, skg = t & 7;                   // staging slot (512 slots/half)
    int abyte = (srow * 128 + skg * 16) ^ ((srow & 7) << 4);

    for (int c = 0; c < 4; ++c) {
        __syncthreads();
        // stage both halves' 64-k chunks (each thread: 1 uint4 per half)
#pragma unroll
        for (int h = 0; h < 2; ++h) {
            const float* g = h2 + srow * 512 + h * 256 + c * 64 + skg * 8;
            float4 p0 = *(const float4*)g;
            float4 p1 = *(const float4*)(g + 4);
            uint4 wv;
            wv.x = cvt_pk(p0.x, p0.y); wv.y = cvt_pk(p0.z, p0.w);
            wv.z = cvt_pk(p1.x, p1.y); wv.w = cvt_pk(p1.z, p1.w);
            *(uint4*)((char*)sA[h] + abyte) = wv;
        }
        __syncthreads();
        // compute own half's chunk
#pragma unroll
        for (int ks = 0; ks < 2; ++ks) {
            int kk = kh * 256 + c * 64 + ks * 32;
            const float* wp = out_W + (size_t)(kk + lg * 8) * 50000 + colc;
            uint4 qv;
            float v0 = wp[0],          v1 = wp[50000];
            float v2 = wp[2 * 50000],  v3 = wp[3 * 50000];
            float v4 = wp[4 * 50000],  v5 = wp[5 * 50000];
            float v6 = wp[6 * 50000],  v7 = wp[7 * 50000];
            qv.x = cvt_pk(v0, v1); qv.y = cvt_pk(v2, v3);
            qv.z = cvt_pk(v4, v5); qv.w = cvt_pk(v6, v7);
            short8 bf = *(short8*)&qv;
            short8 af[4];
#pragma unroll
            for (int rt = 0; rt < 4; ++rt) {
                int row = rt * 16 + li;
                af[rt] = *(short8*)((char*)sA[kh] + ((row * 128 + ks * 64 + lg * 16) ^ sw));
            }
#pragma unroll
            for (int rt = 0; rt < 4; ++rt)
                acc[rt] = __builtin_amdgcn_mfma_f32_16x16x32_bf16(
                    af[rt], bf, acc[rt], 0, 0, 0);
        }
    }
    // cross-half reduce: upper waves park acc in LDS (16KB), lower waves add
    __syncthreads();
    float* red = (float*)sA;                          // 4096 floats x 4 waves
    if (kh == 1) {
#pragma unroll
        for (int rt = 0; rt < 4; ++rt)
            *(f32x4*)&red[wc * 1024 + rt * 256 + l * 4] = acc[rt];
    }
    __syncthreads();
    if (kh == 0 && col < 50000) {
        float bias = out_b[col];
#pragma unroll
        for (int rt = 0; rt < 4; ++rt) {
            f32x4 o = *(f32x4*)&red[wc * 1024 + rt * 256 + l * 4];
#pragma unroll
            for (int r = 0; r < 4; ++r) {
                int row = rt * 16 + lg * 4 + r;
                out[(size_t)row * 50000 + col] = acc[rt][r] + o[r] + bias;
            }
        }
    }
}

// ---------------------------------------------------------------------------
extern "C" void kernel_launch(void* const* d_in, const int* in_sizes, int n_in,
                              void* d_out, int out_size, void* d_ws, size_t ws_size,
                              hipStream_t stream) {
    const int*   cur       = (const int*)d_in[0];
    const float* h0        = (const float*)d_in[1];
    const float* c0        = (const float*)d_in[2];
    const float* enc       = (const float*)d_in[3];
    const float* mask      = (const float*)d_in[4];
    const float* emb_table = (const float*)d_in[5];
    const float* attn_W    = (const float*)d_in[6];
    const float* attn_v    = (const float*)d_in[7];
    const float* cg_W      = (const float*)d_in[8];
    const float* cg_b      = (const float*)d_in[9];
    const float* Wih0      = (const float*)d_in[10];
    const float* Whh0      = (const float*)d_in[11];
    const float* bih0      = (const float*)d_in[12];
    const float* bhh0      = (const float*)d_in[13];
    const float* Wih1      = (const float*)d_in[14];
    const float* Whh1      = (const float*)d_in[15];
    const float* bih1      = (const float*)d_in[16];
    const float* bhh1      = (const float*)d_in[17];
    const float* out_W     = (const float*)d_in[18];
    const float* out_b     = (const float*)d_in[19];
    float* out = (float*)d_out;

    // ws layout (floats) — high-water 1,097,728 floats = 4.39 MB:
    float* w    = (float*)d_ws;
    float* X1   = w;                  // 81920   (dec|emb|-)
    float* X2   = X1 + 81920;         // 81920   (emb | gate | h0[0])
    float* X3   = X2 + 81920;         // 65536   (h1-slot | h0[1])
    float* decW = X3 + 65536;         // 16384
    float* eb   = decW + 16384;       // 65536   raw scores [b][s]
    float* P    = eb + 65536;         // 524288  partials (4x131072); Wt overlays
    float* ctxP = P + 524288;         // 262144  ctx partials
    unsigned short* Wt = (unsigned short*)P;   // bf16 256KB, consumed before P written

    float* outH = out + 3200000;      // h1 then h2
    float* outC = out + 3265536;      // c1 then c2

    hipLaunchKernelGGL(k_prep_conv, dim3(96), dim3(256), 0, stream,
                       cur, h0, emb_table, attn_W, X1, X2, X3, decW, Wt);
    hipLaunchKernelGGL(k_scores_mfma, dim3(1024), dim3(256), 0, stream,
                       enc, Wt, attn_v, decW, eb);
    hipLaunchKernelGGL(k_ctx_partial, dim3(512), dim3(512), 0, stream,
                       eb, mask, enc, ctxP);
    hipLaunchKernelGGL(k_gemm_cg, dim3(8, 4), dim3(1024), 0, stream,
                       X1, ctxP, cg_W, P);
    hipLaunchKernelGGL(k_cg_fin, dim3(128), dim3(256), 0, stream, P, cg_b, ctxP, X2);
    hipLaunchKernelGGL(k_gemm_lstm, dim3(32, 4), dim3(1024), 0, stream,
                       X2, 1280, Wih0, 768, Whh0, 512, 5, P);
    hipLaunchKernelGGL(k_lstm_fin, dim3(128), dim3(256), 0, stream,
                       P, bih0, bhh0, c0, 0, outH, outC, X3);
    hipLaunchKernelGGL(k_gemm_lstm, dim3(32, 4), dim3(1024), 0, stream,
                       X3, 1024, Wih1, 512, Whh1, 512, 4, P);
    hipLaunchKernelGGL(k_lstm_fin, dim3(128), dim3(256), 0, stream,
                       P, bih1, bhh1, c0, 1, outH + 32768, outC + 32768, (float*)nullptr);
    hipLaunchKernelGGL(k_outproj_mfma, dim3(782), dim3(512), 0, stream,
                       outH + 32768, out_W, out_b, out);
}